// Round 3
// baseline (262.153 us; speedup 1.0000x reference)
//
#include <hip/hip_runtime.h>
#include <math.h>

#define S_LEN 4096
#define DM 1024
#define NHEADS 8
#define HDIM 128
#define NSLOTS 2048

typedef __attribute__((ext_vector_type(8))) short bf16x8;
typedef __attribute__((ext_vector_type(4))) float f32x4;
typedef __attribute__((ext_vector_type(16))) float f32x16;

static __device__ __forceinline__ unsigned short f2bf(float f) {
  union { float f; unsigned u; } v; v.f = f;
  unsigned u = v.u;
  return (unsigned short)((u + 0x7fffu + ((u >> 16) & 1u)) >> 16);
}
static __device__ __forceinline__ unsigned pack2(float a, float b) {
  return (unsigned)f2bf(a) | ((unsigned)f2bf(b) << 16);
}
static __device__ __forceinline__ f32x4 mfma16(bf16x8 a, bf16x8 b, f32x4 c) {
  return __builtin_amdgcn_mfma_f32_16x16x32_bf16(a, b, c, 0, 0, 0);
}
static __device__ __forceinline__ f32x16 mfma32(bf16x8 a, bf16x8 b, f32x16 c) {
  return __builtin_amdgcn_mfma_f32_32x32x16_bf16(a, b, c, 0, 0, 0);
}
static __device__ __forceinline__ void gll16(const void* g, void* l) {
  __builtin_amdgcn_global_load_lds(
      (__attribute__((address_space(1))) void*)(void*)(unsigned long long)(const char*)g,
      (__attribute__((address_space(3))) void*)l, 16, 0, 0);
}
// v_exp_f32: D = 2^S0 (ISA §3). Input pre-scaled by log2(e).
static __device__ __forceinline__ float fexp2(float x) {
  float r;
  asm("v_exp_f32 %0, %1" : "=v"(r) : "v"(x));
  return r;
}

// ---- fused prep: cast x | transpose Wq | transpose Wo | prep K | prep V^T ---
__global__ __launch_bounds__(256) void prep_kernel(
    const float* __restrict__ x, const float* __restrict__ Wq,
    const float* __restrict__ Wo, const float* __restrict__ keys,
    const float* __restrict__ values, const float* __restrict__ scale,
    unsigned* __restrict__ xb, unsigned short* __restrict__ wqt,
    unsigned short* __restrict__ wot, unsigned* __restrict__ kbf,
    unsigned short* __restrict__ vt) {
  __shared__ float tile[32][33];
  int b = blockIdx.x, t = threadIdx.x;
  if (b < 4096) {  // cast x -> bf16, float4 per thread
    int i = (b * 256 + t) * 2;  // in float2 units
    float2 v0 = ((const float2*)x)[i];
    float2 v1 = ((const float2*)x)[i + 1];
    xb[i] = pack2(v0.x, v0.y);
    xb[i + 1] = pack2(v1.x, v1.y);
  } else if (b < 6144) {  // transpose+cast Wq / Wo (1024x1024 each)
    int p = b - 4096;
    const float* W = (p < 1024) ? Wq : Wo;
    unsigned short* WT = (p < 1024) ? wqt : wot;
    p &= 1023;
    int n0 = (p & 31) * 32, k0 = (p >> 5) * 32;
    int tx = t & 31, ty = t >> 5;
#pragma unroll
    for (int i = ty; i < 32; i += 8) tile[i][tx] = W[(k0 + i) * DM + n0 + tx];
    __syncthreads();
#pragma unroll
    for (int i = ty; i < 32; i += 8) WT[(n0 + i) * DM + k0 + tx] = f2bf(tile[tx][i]);
  } else if (b < 10240) {  // prep K: normalize + fold attn_scale
    int w = ((b - 6144) * 256 + t) >> 6;  // row 0..16383
    int lane = t & 63;
    int slot = w >> 3, h = w & 7;
    float2 v = ((const float2*)(keys + (size_t)w * HDIM))[lane];
    float ss = v.x * v.x + v.y * v.y;
#pragma unroll
    for (int m = 1; m < 64; m <<= 1) ss += __shfl_xor(ss, m);
    float sc = scale[h] * rsqrtf(ss + 1e-6f);
    kbf[((size_t)h * NSLOTS + slot) * (HDIM / 2) + lane] = pack2(v.x * sc, v.y * sc);
  } else {  // prep V^T: vt[h][d][slot]
    int p = b - 10240;  // 0..2047
    int h = p >> 8, d0 = ((p >> 6) & 3) * 32, s0 = (p & 63) * 32;
    int tx = t & 31, ty = t >> 5;
#pragma unroll
    for (int i = ty; i < 32; i += 8)
      tile[i][tx] = values[((size_t)(s0 + i) * NHEADS + h) * HDIM + d0 + tx];
    __syncthreads();
#pragma unroll
    for (int i = ty; i < 32; i += 8)
      vt[((size_t)h * HDIM + d0 + i) * NSLOTS + s0 + tx] = f2bf(tile[tx][i]);
  }
}

// ---- GEMM: C(MxN) = A(MxK,bf16) * Bt(NxK,bf16)^T. 128x128 tile, 8 waves. ----
// k-major LDS: [kblk 0..3][row 0..127] x 16B -> conflict-free b128 reads.
// FUSE_QNORM: row-normalize per 128-col tile (= one head), scale by log2(e),
// write bf16 to Cq. Else write f32 to Cf.
template <bool FUSE_QNORM>
__global__ __launch_bounds__(512) void gemm_nt_kernel(const unsigned short* __restrict__ A,
                                                      const unsigned short* __restrict__ Bt,
                                                      float* __restrict__ Cf,
                                                      unsigned short* __restrict__ Cq,
                                                      int M, int N, int K) {
  __shared__ unsigned short As2[4096];  // (kblk*128 + row)*8 shorts
  __shared__ unsigned short Bs2[4096];
  __shared__ float ssq[128][2];
  int t = threadIdx.x;
  int wave = t >> 6, lane = t & 63;
  int l16 = lane & 15, quad = lane >> 4;
  int m_blk = blockIdx.y * 128, n_blk = blockIdx.x * 128;
  int wm = (wave & 3) * 32, wn = (wave >> 2) * 64;
  // staging: wave w -> A-inst & B-inst (rowhalf = w&1, kblk = w>>1)
  int row_a = (wave & 1) * 64 + lane, kblk_a = wave >> 1;
  const unsigned short* Ap = A + (size_t)(m_blk + row_a) * K + kblk_a * 8;
  const unsigned short* Bp = Bt + (size_t)(n_blk + row_a) * K + kblk_a * 8;
  unsigned short* Adst = As2 + (kblk_a * 128 + (wave & 1) * 64) * 8;
  unsigned short* Bdst = Bs2 + (kblk_a * 128 + (wave & 1) * 64) * 8;
  f32x4 zero = {0.f, 0.f, 0.f, 0.f};
  f32x4 acc[2][4];
#pragma unroll
  for (int i = 0; i < 2; i++)
#pragma unroll
    for (int j = 0; j < 4; j++) acc[i][j] = zero;

  for (int k0 = 0; k0 < K; k0 += 32) {
    __syncthreads();
    gll16(Ap + k0, Adst);
    gll16(Bp + k0, Bdst);
    __syncthreads();
    bf16x8 af[2], bfr[4];
#pragma unroll
    for (int mt = 0; mt < 2; mt++)
      af[mt] = *(const bf16x8*)(As2 + (quad * 128 + wm + mt * 16 + l16) * 8);
#pragma unroll
    for (int nt = 0; nt < 4; nt++)
      bfr[nt] = *(const bf16x8*)(Bs2 + (quad * 128 + wn + nt * 16 + l16) * 8);
#pragma unroll
    for (int mt = 0; mt < 2; mt++)
#pragma unroll
      for (int nt = 0; nt < 4; nt++) acc[mt][nt] = mfma16(af[mt], bfr[nt], acc[mt][nt]);
  }

  if (FUSE_QNORM) {
#pragma unroll
    for (int mt = 0; mt < 2; mt++)
#pragma unroll
      for (int r = 0; r < 4; r++) {
        float s = 0.f;
#pragma unroll
        for (int nt = 0; nt < 4; nt++) s += acc[mt][nt][r] * acc[mt][nt][r];
#pragma unroll
        for (int d = 1; d < 16; d <<= 1) s += __shfl_xor(s, d);
        if (l16 == 0) ssq[wm + mt * 16 + quad * 4 + r][wave >> 2] = s;
      }
    __syncthreads();
#pragma unroll
    for (int mt = 0; mt < 2; mt++)
#pragma unroll
      for (int r = 0; r < 4; r++) {
        int row = wm + mt * 16 + quad * 4 + r;
        float rs = rsqrtf(ssq[row][0] + ssq[row][1] + 1e-6f) * 1.44269504f;
#pragma unroll
        for (int nt = 0; nt < 4; nt++)
          Cq[(size_t)(m_blk + row) * N + n_blk + wn + nt * 16 + l16] =
              f2bf(acc[mt][nt][r] * rs);
      }
  } else {
#pragma unroll
    for (int mt = 0; mt < 2; mt++)
#pragma unroll
      for (int nt = 0; nt < 4; nt++)
#pragma unroll
        for (int r = 0; r < 4; r++)
          Cf[(size_t)(m_blk + wm + mt * 16 + quad * 4 + r) * N + n_blk + wn + nt * 16 +
             l16] = acc[mt][nt][r];
  }
}

// ---- flash attention vs fixed memory bank -----------------------------------
// 128 thr (2 waves), each wave 32 q-rows via 32x32x16 MFMA. Grid (8, 64).
// LDS K: [kblk 0..15][slot 0..31]x16B; V: [sblk 0..3][d 0..127]x16B (both
// conflict-free). Double-buffered, global_load_lds w16. Static max (unit q,k).
__global__ __launch_bounds__(128, 2) void attn_kernel(const unsigned short* __restrict__ qbf,
                                                      const unsigned short* __restrict__ kbf,
                                                      const unsigned short* __restrict__ vt,
                                                      const float* __restrict__ scale,
                                                      unsigned short* __restrict__ yb) {
  __shared__ unsigned short Ks[2][4096];
  __shared__ unsigned short Vs[2][4096];
  __shared__ unsigned short pbuf[2][32][40];
  int h = blockIdx.x;
  int t = threadIdx.x;
  int wave = t >> 6, lane = t & 63;
  int l32 = lane & 31, h8 = lane >> 5;
  int q0 = blockIdx.y * 64 + wave * 32;
  const unsigned short* Kh = kbf + (size_t)h * NSLOTS * HDIM;
  const unsigned short* Vh = vt + (size_t)h * HDIM * NSLOTS;
  float M2 = fabsf(scale[h]) * 1.44269504f;  // q already carries log2(e)

  bf16x8 aq[8];
  const unsigned short* qrow = qbf + (size_t)(q0 + l32) * DM + h * HDIM + h8 * 8;
#pragma unroll
  for (int dt = 0; dt < 8; dt++) aq[dt] = *(const bf16x8*)(qrow + dt * 16);

  f32x16 zero16 = {};
  f32x16 O[4];
#pragma unroll
  for (int i = 0; i < 4; i++) O[i] = zero16;
  float lsum[16];
#pragma unroll
  for (int r = 0; r < 16; r++) lsum[r] = 0.f;

  auto stage = [&](int n0s, int bb) {
#pragma unroll
    for (int ii = 0; ii < 4; ii++) {
      int i = wave * 4 + ii;
      // K: kblk = 2i + h8, slot = l32
      gll16(Kh + (size_t)(n0s + l32) * HDIM + (2 * i + h8) * 8, &Ks[bb][i * 512]);
      // V: linear r = 64i + lane -> sblk = r>>7, d = r&127
      int rr = 64 * i + lane;
      gll16(Vh + (size_t)(rr & 127) * NSLOTS + n0s + (rr >> 7) * 8, &Vs[bb][i * 512]);
    }
  };

  stage(0, 0);
  for (int c = 0; c < NSLOTS / 32; c++) {
    int b = c & 1;
    __syncthreads();  // drains chunk c's DMA; all waves past chunk c-1
    if (c + 1 < NSLOTS / 32) stage((c + 1) * 32, b ^ 1);

    f32x16 acc = zero16;
#pragma unroll
    for (int dt = 0; dt < 8; dt++) {
      bf16x8 kf = *(const bf16x8*)(&Ks[b][((2 * dt + h8) * 32 + l32) * 8]);
      acc = mfma32(aq[dt], kf, acc);
    }
#pragma unroll
    for (int r = 0; r < 16; r++) {
      float p = fexp2(acc[r] - M2);
      lsum[r] += p;
      pbuf[wave][(r & 3) + 8 * (r >> 2) + 4 * h8][l32] = f2bf(p);
    }
    bf16x8 pa[2];
#pragma unroll
    for (int ks = 0; ks < 2; ks++)
      pa[ks] = *(const bf16x8*)(&pbuf[wave][l32][ks * 16 + h8 * 8]);
#pragma unroll
    for (int nt = 0; nt < 4; nt++) {
      f32x16 o = O[nt];
#pragma unroll
      for (int ks = 0; ks < 2; ks++) {
        bf16x8 vf = *(const bf16x8*)(&Vs[b][((2 * ks + h8) * 128 + nt * 32 + l32) * 8]);
        o = mfma32(pa[ks], vf, o);
      }
      O[nt] = o;
    }
  }

  float inv[16];
#pragma unroll
  for (int r = 0; r < 16; r++) {
    float s = lsum[r];
#pragma unroll
    for (int d = 1; d < 32; d <<= 1) s += __shfl_xor(s, d);
    inv[r] = 1.0f / s;
  }
#pragma unroll
  for (int nt = 0; nt < 4; nt++)
#pragma unroll
    for (int r = 0; r < 16; r++) {
      int row = (r & 3) + 8 * (r >> 2) + 4 * h8;
      yb[(size_t)(q0 + row) * DM + h * HDIM + nt * 32 + l32] = f2bf(O[nt][r] * inv[r]);
    }
}

// ---- launcher ---------------------------------------------------------------

extern "C" void kernel_launch(void* const* d_in, const int* in_sizes, int n_in,
                              void* d_out, int out_size, void* d_ws, size_t ws_size,
                              hipStream_t stream) {
  const float* x = (const float*)d_in[0];
  const float* Wq = (const float*)d_in[1];
  const float* keys = (const float*)d_in[2];
  const float* values = (const float*)d_in[3];
  const float* attn_scale = (const float*)d_in[4];
  const float* Wo = (const float*)d_in[5];
  float* out = (float*)d_out;

  char* ws = (char*)d_ws;
  unsigned short* xb = (unsigned short*)(ws);                   // 8 MB
  unsigned short* wqt = (unsigned short*)(ws + (8ull << 20));   // 2 MB
  unsigned short* wot = (unsigned short*)(ws + (10ull << 20));  // 2 MB
  unsigned short* kbf = (unsigned short*)(ws + (12ull << 20));  // 4 MB
  unsigned short* vt = (unsigned short*)(ws + (16ull << 20));   // 4 MB
  unsigned short* qbf = (unsigned short*)(ws + (20ull << 20));  // 8 MB
  unsigned short* yb = (unsigned short*)(ws + (28ull << 20));   // 8 MB (36 total)

  prep_kernel<<<12288, 256, 0, stream>>>(x, Wq, Wo, keys, values, attn_scale,
                                         (unsigned*)xb, wqt, wot, (unsigned*)kbf, vt);
  gemm_nt_kernel<true><<<dim3(8, 32), 512, 0, stream>>>(xb, wqt, nullptr, qbf,
                                                        S_LEN, DM, DM);
  attn_kernel<<<dim3(8, 64), 128, 0, stream>>>(qbf, kbf, vt, attn_scale, yb);
  gemm_nt_kernel<false><<<dim3(8, 32), 512, 0, stream>>>(yb, wot, out, nullptr,
                                                         S_LEN, DM, DM);
}

// Round 4
// 259.071 us; speedup vs baseline: 1.0119x; 1.0119x over previous
//
#include <hip/hip_runtime.h>
#include <math.h>

#define S_LEN 4096
#define DM 1024
#define NHEADS 8
#define HDIM 128
#define NSLOTS 2048

typedef __attribute__((ext_vector_type(8))) short bf16x8;
typedef __attribute__((ext_vector_type(4))) float f32x4;
typedef __attribute__((ext_vector_type(16))) float f32x16;

static __device__ __forceinline__ unsigned short f2bf(float f) {
  union { float f; unsigned u; } v; v.f = f;
  unsigned u = v.u;
  return (unsigned short)((u + 0x7fffu + ((u >> 16) & 1u)) >> 16);
}
static __device__ __forceinline__ unsigned pack2(float a, float b) {
  return (unsigned)f2bf(a) | ((unsigned)f2bf(b) << 16);
}
static __device__ __forceinline__ f32x4 mfma16(bf16x8 a, bf16x8 b, f32x4 c) {
  return __builtin_amdgcn_mfma_f32_16x16x32_bf16(a, b, c, 0, 0, 0);
}
static __device__ __forceinline__ f32x16 mfma32(bf16x8 a, bf16x8 b, f32x16 c) {
  return __builtin_amdgcn_mfma_f32_32x32x16_bf16(a, b, c, 0, 0, 0);
}
static __device__ __forceinline__ void gll16(const void* g, void* l) {
  __builtin_amdgcn_global_load_lds(
      (__attribute__((address_space(1))) void*)(void*)(unsigned long long)(const char*)g,
      (__attribute__((address_space(3))) void*)l, 16, 0, 0);
}
// v_exp_f32: D = 2^S0. Inputs pre-scaled by log2(e).
static __device__ __forceinline__ float fexp2(float x) {
  float r;
  asm("v_exp_f32 %0, %1" : "=v"(r) : "v"(x));
  return r;
}

// ---- fused prep: cast x | transpose Wq | transpose Wo | prep K | prep V^T ---
__global__ __launch_bounds__(256) void prep_kernel(
    const float* __restrict__ x, const float* __restrict__ Wq,
    const float* __restrict__ Wo, const float* __restrict__ keys,
    const float* __restrict__ values, const float* __restrict__ scale,
    unsigned* __restrict__ xb, unsigned short* __restrict__ wqt,
    unsigned short* __restrict__ wot, unsigned* __restrict__ kbf,
    unsigned short* __restrict__ vt) {
  __shared__ float tile[32][33];
  int b = blockIdx.x, t = threadIdx.x;
  if (b < 4096) {  // cast x -> bf16
    int i = (b * 256 + t) * 2;
    float2 v0 = ((const float2*)x)[i];
    float2 v1 = ((const float2*)x)[i + 1];
    xb[i] = pack2(v0.x, v0.y);
    xb[i + 1] = pack2(v1.x, v1.y);
  } else if (b < 6144) {  // transpose+cast Wq / Wo
    int p = b - 4096;
    const float* W = (p < 1024) ? Wq : Wo;
    unsigned short* WT = (p < 1024) ? wqt : wot;
    p &= 1023;
    int n0 = (p & 31) * 32, k0 = (p >> 5) * 32;
    int tx = t & 31, ty = t >> 5;
#pragma unroll
    for (int i = ty; i < 32; i += 8) tile[i][tx] = W[(k0 + i) * DM + n0 + tx];
    __syncthreads();
#pragma unroll
    for (int i = ty; i < 32; i += 8) WT[(n0 + i) * DM + k0 + tx] = f2bf(tile[tx][i]);
  } else if (b < 10240) {  // prep K: normalize + fold attn_scale
    int w = ((b - 6144) * 256 + t) >> 6;
    int lane = t & 63;
    int slot = w >> 3, h = w & 7;
    float2 v = ((const float2*)(keys + (size_t)w * HDIM))[lane];
    float ss = v.x * v.x + v.y * v.y;
#pragma unroll
    for (int m = 1; m < 64; m <<= 1) ss += __shfl_xor(ss, m);
    float sc = scale[h] * rsqrtf(ss + 1e-6f);
    kbf[((size_t)h * NSLOTS + slot) * (HDIM / 2) + lane] = pack2(v.x * sc, v.y * sc);
  } else {  // prep V^T: vt[h][d][slot]
    int p = b - 10240;
    int h = p >> 8, d0 = ((p >> 6) & 3) * 32, s0 = (p & 63) * 32;
    int tx = t & 31, ty = t >> 5;
#pragma unroll
    for (int i = ty; i < 32; i += 8)
      tile[i][tx] = values[((size_t)(s0 + i) * NHEADS + h) * HDIM + d0 + tx];
    __syncthreads();
#pragma unroll
    for (int i = ty; i < 32; i += 8)
      vt[((size_t)h * HDIM + d0 + i) * NSLOTS + s0 + tx] = f2bf(tile[tx][i]);
  }
}

// ---- GEMM: C(MxN) = A(MxK,bf16) * Bt(NxK,bf16)^T. 64x128 tile, 4 waves. -----
// Grid (N/128, M/64) = 512 blocks -> 2 blocks/CU. k-major conflict-free LDS.
// FUSE_QNORM: row-normalize per 128-col tile (one head), fold log2(e), bf16 out.
template <bool FUSE_QNORM>
__global__ __launch_bounds__(256) void gemm_nt_kernel(const unsigned short* __restrict__ A,
                                                      const unsigned short* __restrict__ Bt,
                                                      float* __restrict__ Cf,
                                                      unsigned short* __restrict__ Cq,
                                                      int M, int N, int K) {
  __shared__ __align__(16) unsigned short As2[2048];  // (kblk*64 + row)*8
  __shared__ __align__(16) unsigned short Bs2[4096];  // (kblk*128 + row)*8
  __shared__ float ssq[64][2];
  int t = threadIdx.x;
  int wave = t >> 6, lane = t & 63;
  int l16 = lane & 15, quad = lane >> 4;
  int m_blk = blockIdx.y * 64, n_blk = blockIdx.x * 128;
  int wm = (wave & 1) * 32, wn = (wave >> 1) * 64;
  const unsigned short* Ap = A + (size_t)(m_blk + lane) * K + wave * 8;
  const unsigned short* Bp0 = Bt + (size_t)(n_blk + lane) * K + wave * 8;
  const unsigned short* Bp1 = Bt + (size_t)(n_blk + 64 + lane) * K + wave * 8;
  f32x4 zero = {0.f, 0.f, 0.f, 0.f};
  f32x4 acc[2][4];
#pragma unroll
  for (int i = 0; i < 2; i++)
#pragma unroll
    for (int j = 0; j < 4; j++) acc[i][j] = zero;

  for (int k0 = 0; k0 < K; k0 += 32) {
    __syncthreads();
    gll16(Ap + k0, &As2[wave * 512]);
    gll16(Bp0 + k0, &Bs2[(2 * wave) * 512]);
    gll16(Bp1 + k0, &Bs2[(2 * wave + 1) * 512]);
    __syncthreads();
    bf16x8 af[2], bfr[4];
#pragma unroll
    for (int mt = 0; mt < 2; mt++)
      af[mt] = *(const bf16x8*)&As2[(quad * 64 + wm + mt * 16 + l16) * 8];
#pragma unroll
    for (int nt = 0; nt < 4; nt++)
      bfr[nt] = *(const bf16x8*)&Bs2[(quad * 128 + wn + nt * 16 + l16) * 8];
#pragma unroll
    for (int mt = 0; mt < 2; mt++)
#pragma unroll
      for (int nt = 0; nt < 4; nt++) acc[mt][nt] = mfma16(af[mt], bfr[nt], acc[mt][nt]);
  }

  if (FUSE_QNORM) {
#pragma unroll
    for (int mt = 0; mt < 2; mt++)
#pragma unroll
      for (int r = 0; r < 4; r++) {
        float s = 0.f;
#pragma unroll
        for (int nt = 0; nt < 4; nt++) s += acc[mt][nt][r] * acc[mt][nt][r];
#pragma unroll
        for (int d = 1; d < 16; d <<= 1) s += __shfl_xor(s, d);
        if (l16 == 0) ssq[wm + mt * 16 + quad * 4 + r][wave >> 1] = s;
      }
    __syncthreads();
#pragma unroll
    for (int mt = 0; mt < 2; mt++)
#pragma unroll
      for (int r = 0; r < 4; r++) {
        int row = wm + mt * 16 + quad * 4 + r;
        float rs = rsqrtf(ssq[row][0] + ssq[row][1] + 1e-6f) * 1.44269504f;
#pragma unroll
        for (int nt = 0; nt < 4; nt++)
          Cq[(size_t)(m_blk + row) * N + n_blk + wn + nt * 16 + l16] =
              f2bf(acc[mt][nt][r] * rs);
      }
  } else {
#pragma unroll
    for (int mt = 0; mt < 2; mt++)
#pragma unroll
      for (int nt = 0; nt < 4; nt++)
#pragma unroll
        for (int r = 0; r < 4; r++)
          Cf[(size_t)(m_blk + wm + mt * 16 + quad * 4 + r) * N + n_blk + wn + nt * 16 +
             l16] = acc[mt][nt][r];
  }
}

// ---- flash attention vs fixed memory bank -----------------------------------
// 256 thr = 2 q-groups x 2 slot-splits; 32 q-rows/wave via 32x32x16 MFMA.
// 64-slot chunks: K staged to LDS (double-buffered, conflict-free), V read
// DIRECT from global (16B contiguous B-frags, L2-resident per head).
// Static softmax max; split-K partials (O, lsum) combined via LDS at end.
__global__ __launch_bounds__(256, 2) void attn_kernel(const unsigned short* __restrict__ qbf,
                                                      const unsigned short* __restrict__ kbf,
                                                      const unsigned short* __restrict__ vt,
                                                      const float* __restrict__ scale,
                                                      unsigned short* __restrict__ yb) {
  __shared__ __align__(16) char smem[43008];  // loop: Ks 32KB + pbuf 10KB; epi: Oc 32KB + Lc 8KB
  unsigned short(*Ks)[8192] = (unsigned short(*)[8192])smem;
  unsigned short(*pbuf)[32][40] = (unsigned short(*)[32][40])(smem + 32768);
  int h = blockIdx.x, t = threadIdx.x;
  int wave = t >> 6, lane = t & 63;
  int l32 = lane & 31, h8 = lane >> 5;
  int g = wave >> 1, s = wave & 1;
  int q0 = blockIdx.y * 64 + g * 32;
  const unsigned short* Kh = kbf + (size_t)h * NSLOTS * HDIM;
  const unsigned short* Vh = vt + (size_t)h * HDIM * NSLOTS;
  float M2 = fabsf(scale[h]) * 1.44269504f;  // q carries log2(e)

  bf16x8 aq[8];
  const unsigned short* qrow = qbf + (size_t)(q0 + l32) * DM + h * HDIM + h8 * 8;
#pragma unroll
  for (int dt = 0; dt < 8; dt++) aq[dt] = *(const bf16x8*)(qrow + dt * 16);

  f32x16 zero16 = {};
  f32x16 O[4];
#pragma unroll
  for (int i = 0; i < 4; i++) O[i] = zero16;
  float lsum[16];
#pragma unroll
  for (int r = 0; r < 16; r++) lsum[r] = 0.f;

  auto stage = [&](int n0, int b) {
#pragma unroll
    for (int ii = 0; ii < 4; ii++) {
      int j = wave * 4 + ii;        // 0..15
      int sK = j >> 3, jp = j & 7;  // half, kblk pair
      gll16(Kh + (size_t)(n0 + sK * 32 + l32) * HDIM + (2 * jp + h8) * 8, &Ks[b][j * 512]);
    }
  };

  stage(0, 0);
  for (int c = 0; c < NSLOTS / 64; c++) {
    int b = c & 1;
    __syncthreads();  // drain chunk c DMA; all waves past buffer b
    if (c + 1 < NSLOTS / 64) stage((c + 1) * 64, b ^ 1);
    int slot0 = c * 64 + s * 32;

    f32x16 acc = zero16;
#pragma unroll
    for (int dt = 0; dt < 8; dt++) {
      bf16x8 kf = *(const bf16x8*)&Ks[b][s * 4096 + ((2 * dt + h8) * 32 + l32) * 8];
      acc = mfma32(aq[dt], kf, acc);
    }
#pragma unroll
    for (int r = 0; r < 16; r++) {
      float p = fexp2(acc[r] - M2);
      lsum[r] += p;
      pbuf[wave][(r & 3) + 8 * (r >> 2) + 4 * h8][l32] = f2bf(p);
    }
    bf16x8 pa[2];
#pragma unroll
    for (int ks = 0; ks < 2; ks++)
      pa[ks] = *(const bf16x8*)&pbuf[wave][l32][ks * 16 + h8 * 8];
#pragma unroll
    for (int nt = 0; nt < 4; nt++) {
      f32x16 o = O[nt];
#pragma unroll
      for (int ks = 0; ks < 2; ks++) {
        const unsigned short* vp =
            Vh + (size_t)(nt * 32 + l32) * NSLOTS + slot0 + ks * 16 + h8 * 8;
        o = mfma32(pa[ks], *(const bf16x8*)vp, o);
      }
      O[nt] = o;
    }
  }

  // ---- split-K combine (exact: static max, no rescale) ----
  __syncthreads();
  float(*Oc)[32][128] = (float(*)[32][128])smem;
  float(*Lc)[32][32] = (float(*)[32][32])(smem + 32768);
  if (s == 1) {
#pragma unroll
    for (int nt = 0; nt < 4; nt++)
#pragma unroll
      for (int r = 0; r < 16; r++)
        Oc[g][(r & 3) + 8 * (r >> 2) + 4 * h8][nt * 32 + l32] = O[nt][r];
#pragma unroll
    for (int r = 0; r < 16; r++) Lc[g][(r & 3) + 8 * (r >> 2) + 4 * h8][l32] = lsum[r];
  }
  __syncthreads();
  if (s == 0) {
#pragma unroll
    for (int r = 0; r < 16; r++) {
      int row = (r & 3) + 8 * (r >> 2) + 4 * h8;
      float sum = lsum[r] + Lc[g][row][l32];
#pragma unroll
      for (int d = 1; d < 32; d <<= 1) sum += __shfl_xor(sum, d);
      float inv = 1.0f / sum;
#pragma unroll
      for (int nt = 0; nt < 4; nt++) {
        float v = O[nt][r] + Oc[g][row][nt * 32 + l32];
        yb[(size_t)(q0 + row) * DM + h * HDIM + nt * 32 + l32] = f2bf(v * inv);
      }
    }
  }
}

// ---- launcher ---------------------------------------------------------------

extern "C" void kernel_launch(void* const* d_in, const int* in_sizes, int n_in,
                              void* d_out, int out_size, void* d_ws, size_t ws_size,
                              hipStream_t stream) {
  const float* x = (const float*)d_in[0];
  const float* Wq = (const float*)d_in[1];
  const float* keys = (const float*)d_in[2];
  const float* values = (const float*)d_in[3];
  const float* attn_scale = (const float*)d_in[4];
  const float* Wo = (const float*)d_in[5];
  float* out = (float*)d_out;

  char* ws = (char*)d_ws;
  unsigned short* xb = (unsigned short*)(ws);                   // 8 MB
  unsigned short* wqt = (unsigned short*)(ws + (8ull << 20));   // 2 MB
  unsigned short* wot = (unsigned short*)(ws + (10ull << 20));  // 2 MB
  unsigned short* kbf = (unsigned short*)(ws + (12ull << 20));  // 4 MB
  unsigned short* vt = (unsigned short*)(ws + (16ull << 20));   // 4 MB
  unsigned short* qbf = (unsigned short*)(ws + (20ull << 20));  // 8 MB
  unsigned short* yb = (unsigned short*)(ws + (28ull << 20));   // 8 MB

  prep_kernel<<<12288, 256, 0, stream>>>(x, Wq, Wo, keys, values, attn_scale,
                                         (unsigned*)xb, wqt, wot, (unsigned*)kbf, vt);
  gemm_nt_kernel<true><<<dim3(8, 64), 256, 0, stream>>>(xb, wqt, nullptr, qbf,
                                                        S_LEN, DM, DM);
  attn_kernel<<<dim3(8, 64), 256, 0, stream>>>(qbf, kbf, vt, attn_scale, yb);
  gemm_nt_kernel<false><<<dim3(8, 64), 256, 0, stream>>>(yb, wot, out, nullptr,
                                                         S_LEN, DM, DM);
}

// Round 5
// 246.598 us; speedup vs baseline: 1.0631x; 1.0506x over previous
//
#include <hip/hip_runtime.h>
#include <math.h>

#define S_LEN 4096
#define DM 1024
#define NHEADS 8
#define HDIM 128
#define NSLOTS 2048

typedef __attribute__((ext_vector_type(8))) short bf16x8;
typedef __attribute__((ext_vector_type(4))) float f32x4;
typedef __attribute__((ext_vector_type(16))) float f32x16;

static __device__ __forceinline__ unsigned short f2bf(float f) {
  union { float f; unsigned u; } v; v.f = f;
  unsigned u = v.u;
  return (unsigned short)((u + 0x7fffu + ((u >> 16) & 1u)) >> 16);
}
static __device__ __forceinline__ unsigned pack2(float a, float b) {
  return (unsigned)f2bf(a) | ((unsigned)f2bf(b) << 16);
}
static __device__ __forceinline__ f32x4 mfma16(bf16x8 a, bf16x8 b, f32x4 c) {
  return __builtin_amdgcn_mfma_f32_16x16x32_bf16(a, b, c, 0, 0, 0);
}
static __device__ __forceinline__ f32x16 mfma32(bf16x8 a, bf16x8 b, f32x16 c) {
  return __builtin_amdgcn_mfma_f32_32x32x16_bf16(a, b, c, 0, 0, 0);
}
static __device__ __forceinline__ void gll16(const void* g, void* l) {
  __builtin_amdgcn_global_load_lds(
      (__attribute__((address_space(1))) void*)(void*)(unsigned long long)(const char*)g,
      (__attribute__((address_space(3))) void*)l, 16, 0, 0);
}
// v_exp_f32: D = 2^S0. Inputs pre-scaled by log2(e).
static __device__ __forceinline__ float fexp2(float x) {
  float r;
  asm("v_exp_f32 %0, %1" : "=v"(r) : "v"(x));
  return r;
}

// ---- fused prep: cast x | transpose Wq | transpose Wo | prep K | prep V^T ---
__global__ __launch_bounds__(256) void prep_kernel(
    const float* __restrict__ x, const float* __restrict__ Wq,
    const float* __restrict__ Wo, const float* __restrict__ keys,
    const float* __restrict__ values, const float* __restrict__ scale,
    unsigned* __restrict__ xb, unsigned short* __restrict__ wqt,
    unsigned short* __restrict__ wot, unsigned* __restrict__ kbf,
    unsigned short* __restrict__ vt) {
  __shared__ float tile[32][33];
  int b = blockIdx.x, t = threadIdx.x;
  if (b < 4096) {  // cast x -> bf16
    int i = (b * 256 + t) * 2;
    float2 v0 = ((const float2*)x)[i];
    float2 v1 = ((const float2*)x)[i + 1];
    xb[i] = pack2(v0.x, v0.y);
    xb[i + 1] = pack2(v1.x, v1.y);
  } else if (b < 6144) {  // transpose+cast Wq / Wo
    int p = b - 4096;
    const float* W = (p < 1024) ? Wq : Wo;
    unsigned short* WT = (p < 1024) ? wqt : wot;
    p &= 1023;
    int n0 = (p & 31) * 32, k0 = (p >> 5) * 32;
    int tx = t & 31, ty = t >> 5;
#pragma unroll
    for (int i = ty; i < 32; i += 8) tile[i][tx] = W[(k0 + i) * DM + n0 + tx];
    __syncthreads();
#pragma unroll
    for (int i = ty; i < 32; i += 8) WT[(n0 + i) * DM + k0 + tx] = f2bf(tile[tx][i]);
  } else if (b < 10240) {  // prep K: normalize + fold attn_scale
    int w = ((b - 6144) * 256 + t) >> 6;
    int lane = t & 63;
    int slot = w >> 3, h = w & 7;
    float2 v = ((const float2*)(keys + (size_t)w * HDIM))[lane];
    float ss = v.x * v.x + v.y * v.y;
#pragma unroll
    for (int m = 1; m < 64; m <<= 1) ss += __shfl_xor(ss, m);
    float sc = scale[h] * rsqrtf(ss + 1e-6f);
    kbf[((size_t)h * NSLOTS + slot) * (HDIM / 2) + lane] = pack2(v.x * sc, v.y * sc);
  } else {  // prep V^T: vt[h][d][slot]
    int p = b - 10240;
    int h = p >> 8, d0 = ((p >> 6) & 3) * 32, s0 = (p & 63) * 32;
    int tx = t & 31, ty = t >> 5;
#pragma unroll
    for (int i = ty; i < 32; i += 8)
      tile[i][tx] = values[((size_t)(s0 + i) * NHEADS + h) * HDIM + d0 + tx];
    __syncthreads();
#pragma unroll
    for (int i = ty; i < 32; i += 8)
      vt[((size_t)h * HDIM + d0 + i) * NSLOTS + s0 + tx] = f2bf(tile[tx][i]);
  }
}

// ---- GEMM: C(MxN) = A(MxK,bf16) * Bt(NxK,bf16)^T. 64x128 tile, 4 waves. -----
// BK=64, double-buffered LDS (one barrier per iter, DMA overlaps compute).
// k-major conflict-free LDS: A [kblk8 0..7][row 0..63]x16B, B [..][row 0..127].
// FUSE_QNORM: row-normalize per 128-col tile (one head), fold log2(e), bf16 out.
template <bool FUSE_QNORM>
__global__ __launch_bounds__(256) void gemm_nt_kernel(const unsigned short* __restrict__ A,
                                                      const unsigned short* __restrict__ Bt,
                                                      float* __restrict__ Cf,
                                                      unsigned short* __restrict__ Cq,
                                                      int M, int N, int K) {
  __shared__ __align__(16) unsigned short As2[2][4096];  // 2 x 8KB
  __shared__ __align__(16) unsigned short Bs2[2][8192];  // 2 x 16KB
  __shared__ float ssq[64][2];
  int t = threadIdx.x;
  int wave = t >> 6, lane = t & 63;
  int l16 = lane & 15, quad = lane >> 4;
  int m_blk = blockIdx.y * 64, n_blk = blockIdx.x * 128;
  int wm = (wave & 1) * 32, wn = (wave >> 1) * 64;
  f32x4 zero = {0.f, 0.f, 0.f, 0.f};
  f32x4 acc[2][4];
#pragma unroll
  for (int i = 0; i < 2; i++)
#pragma unroll
    for (int j = 0; j < 4; j++) acc[i][j] = zero;

  auto stage = [&](int k0, int b) {
#pragma unroll
    for (int i = 0; i < 2; i++) {  // A: kblk8 = 2*wave + i
      int kb = wave * 2 + i;
      gll16(A + (size_t)(m_blk + lane) * K + k0 + kb * 8, &As2[b][kb * 512]);
    }
#pragma unroll
    for (int i = 0; i < 4; i++) {  // B: j -> kblk8 = j&7, rowhalf = j>>3
      int j = wave * 4 + i;
      int kb = j & 7, rh = j >> 3;
      gll16(Bt + (size_t)(n_blk + rh * 64 + lane) * K + k0 + kb * 8,
            &Bs2[b][(kb * 128 + rh * 64) * 8]);
    }
  };

  stage(0, 0);
  for (int k0 = 0; k0 < K; k0 += 64) {
    int b = (k0 >> 6) & 1;
    __syncthreads();  // drains this buffer's DMA; all waves done reading b^1
    if (k0 + 64 < K) stage(k0 + 64, b ^ 1);
#pragma unroll
    for (int kk = 0; kk < 2; kk++) {
      bf16x8 af[2], bfr[4];
#pragma unroll
      for (int mt = 0; mt < 2; mt++)
        af[mt] = *(const bf16x8*)&As2[b][((kk * 4 + quad) * 64 + wm + mt * 16 + l16) * 8];
#pragma unroll
      for (int nt = 0; nt < 4; nt++)
        bfr[nt] = *(const bf16x8*)&Bs2[b][((kk * 4 + quad) * 128 + wn + nt * 16 + l16) * 8];
#pragma unroll
      for (int mt = 0; mt < 2; mt++)
#pragma unroll
        for (int nt = 0; nt < 4; nt++) acc[mt][nt] = mfma16(af[mt], bfr[nt], acc[mt][nt]);
    }
  }

  if (FUSE_QNORM) {
#pragma unroll
    for (int mt = 0; mt < 2; mt++)
#pragma unroll
      for (int r = 0; r < 4; r++) {
        float s = 0.f;
#pragma unroll
        for (int nt = 0; nt < 4; nt++) s += acc[mt][nt][r] * acc[mt][nt][r];
#pragma unroll
        for (int d = 1; d < 16; d <<= 1) s += __shfl_xor(s, d);
        if (l16 == 0) ssq[wm + mt * 16 + quad * 4 + r][wave >> 1] = s;
      }
    __syncthreads();
#pragma unroll
    for (int mt = 0; mt < 2; mt++)
#pragma unroll
      for (int r = 0; r < 4; r++) {
        int row = wm + mt * 16 + quad * 4 + r;
        float rs = rsqrtf(ssq[row][0] + ssq[row][1] + 1e-6f) * 1.44269504f;
#pragma unroll
        for (int nt = 0; nt < 4; nt++)
          Cq[(size_t)(m_blk + row) * N + n_blk + wn + nt * 16 + l16] =
              f2bf(acc[mt][nt][r] * rs);
      }
  } else {
#pragma unroll
    for (int mt = 0; mt < 2; mt++)
#pragma unroll
      for (int nt = 0; nt < 4; nt++)
#pragma unroll
        for (int r = 0; r < 4; r++)
          Cf[(size_t)(m_blk + wm + mt * 16 + quad * 4 + r) * N + n_blk + wn + nt * 16 +
             l16] = acc[mt][nt][r];
  }
}

// ---- flash attention vs fixed memory bank -----------------------------------
// 256 thr = 2 q-groups x 2 slot-splits; 32 q-rows/wave via 32x32x16 MFMA.
// 64-slot chunks. K: LDS double-buffered DMA. V: VGPR double-buffered prefetch
// (loads issued one chunk ahead; the vmcnt(0)-before-barrier drain makes them
// free at consumption). QK accumulator split into 2 chains (4-deep not 8).
// Static softmax max; split-K partials combined via LDS at the end.
__global__ __launch_bounds__(256, 2) void attn_kernel(const unsigned short* __restrict__ qbf,
                                                      const unsigned short* __restrict__ kbf,
                                                      const unsigned short* __restrict__ vt,
                                                      const float* __restrict__ scale,
                                                      unsigned short* __restrict__ yb) {
  __shared__ __align__(16) char smem[43008];  // loop: Ks 32KB + pbuf 10KB; epi: Oc 32KB + Lc 8KB
  unsigned short(*Ks)[8192] = (unsigned short(*)[8192])smem;
  unsigned short(*pbuf)[32][40] = (unsigned short(*)[32][40])(smem + 32768);
  int h = blockIdx.x, t = threadIdx.x;
  int wave = t >> 6, lane = t & 63;
  int l32 = lane & 31, h8 = lane >> 5;
  int g = wave >> 1, s = wave & 1;
  int q0 = blockIdx.y * 64 + g * 32;
  const unsigned short* Kh = kbf + (size_t)h * NSLOTS * HDIM;
  const unsigned short* Vh = vt + (size_t)h * HDIM * NSLOTS;
  float M2 = fabsf(scale[h]) * 1.44269504f;  // q carries log2(e)

  bf16x8 aq[8];
  const unsigned short* qrow = qbf + (size_t)(q0 + l32) * DM + h * HDIM + h8 * 8;
#pragma unroll
  for (int dt = 0; dt < 8; dt++) aq[dt] = *(const bf16x8*)(qrow + dt * 16);

  f32x16 zero16 = {};
  f32x16 O[4];
#pragma unroll
  for (int i = 0; i < 4; i++) O[i] = zero16;
  float lsum[16];
#pragma unroll
  for (int r = 0; r < 16; r++) lsum[r] = 0.f;

  auto stage = [&](int n0, int b) {
#pragma unroll
    for (int ii = 0; ii < 4; ii++) {
      int j = wave * 4 + ii;        // 0..15
      int sK = j >> 3, jp = j & 7;  // split-half, kblk pair
      gll16(Kh + (size_t)(n0 + sK * 32 + l32) * HDIM + (2 * jp + h8) * 8, &Ks[b][j * 512]);
    }
  };
  auto loadV = [&](bf16x8(&V)[8], int n0) {
#pragma unroll
    for (int nt = 0; nt < 4; nt++)
#pragma unroll
      for (int ks = 0; ks < 2; ks++)
        V[nt * 2 + ks] = *(const bf16x8*)(Vh + (size_t)(nt * 32 + l32) * NSLOTS + n0 +
                                          s * 32 + ks * 16 + h8 * 8);
  };
  auto body = [&](const unsigned short* Kbuf, bf16x8(&V)[8]) {
    f32x16 acc0 = zero16, acc1 = zero16;
#pragma unroll
    for (int dt = 0; dt < 4; dt++) {
      bf16x8 k0 = *(const bf16x8*)&Kbuf[s * 4096 + ((4 * dt + h8) * 32 + l32) * 8];
      bf16x8 k1 = *(const bf16x8*)&Kbuf[s * 4096 + ((4 * dt + 2 + h8) * 32 + l32) * 8];
      acc0 = mfma32(aq[2 * dt], k0, acc0);
      acc1 = mfma32(aq[2 * dt + 1], k1, acc1);
    }
    f32x16 acc = acc0 + acc1;
#pragma unroll
    for (int r = 0; r < 16; r++) {
      float p = fexp2(acc[r] - M2);
      lsum[r] += p;
      pbuf[wave][(r & 3) + 8 * (r >> 2) + 4 * h8][l32] = f2bf(p);
    }
    bf16x8 pa[2];
#pragma unroll
    for (int ks = 0; ks < 2; ks++)
      pa[ks] = *(const bf16x8*)&pbuf[wave][l32][ks * 16 + h8 * 8];
#pragma unroll
    for (int nt = 0; nt < 4; nt++) {
      f32x16 o = O[nt];
      o = mfma32(pa[0], V[nt * 2 + 0], o);
      o = mfma32(pa[1], V[nt * 2 + 1], o);
      O[nt] = o;
    }
  };

  bf16x8 Vreg0[8], Vreg1[8];
  constexpr int NC = NSLOTS / 64;  // 32
  stage(0, 0);
  loadV(Vreg0, 0);
  for (int cc = 0; cc < NC; cc += 2) {
    __syncthreads();  // drains chunk cc K-DMA + Vreg0 loads
    if (cc + 1 < NC) {
      stage((cc + 1) * 64, 1);
      loadV(Vreg1, (cc + 1) * 64);
    }
    body(&Ks[0][0], Vreg0);
    __syncthreads();  // drains chunk cc+1 K-DMA + Vreg1 loads
    if (cc + 2 < NC) {
      stage((cc + 2) * 64, 0);
      loadV(Vreg0, (cc + 2) * 64);
    }
    body(&Ks[1][0], Vreg1);
  }

  // ---- split-K combine (exact: static max, no rescale) ----
  __syncthreads();
  float(*Oc)[32][128] = (float(*)[32][128])smem;
  float(*Lc)[32][32] = (float(*)[32][32])(smem + 32768);
  if (s == 1) {
#pragma unroll
    for (int nt = 0; nt < 4; nt++)
#pragma unroll
      for (int r = 0; r < 16; r++)
        Oc[g][(r & 3) + 8 * (r >> 2) + 4 * h8][nt * 32 + l32] = O[nt][r];
#pragma unroll
    for (int r = 0; r < 16; r++) Lc[g][(r & 3) + 8 * (r >> 2) + 4 * h8][l32] = lsum[r];
  }
  __syncthreads();
  if (s == 0) {
#pragma unroll
    for (int r = 0; r < 16; r++) {
      int row = (r & 3) + 8 * (r >> 2) + 4 * h8;
      float sum = lsum[r] + Lc[g][row][l32];
#pragma unroll
      for (int d = 1; d < 32; d <<= 1) sum += __shfl_xor(sum, d);
      float inv = 1.0f / sum;
#pragma unroll
      for (int nt = 0; nt < 4; nt++) {
        float v = O[nt][r] + Oc[g][row][nt * 32 + l32];
        yb[(size_t)(q0 + row) * DM + h * HDIM + nt * 32 + l32] = f2bf(v * inv);
      }
    }
  }
}

// ---- launcher ---------------------------------------------------------------

extern "C" void kernel_launch(void* const* d_in, const int* in_sizes, int n_in,
                              void* d_out, int out_size, void* d_ws, size_t ws_size,
                              hipStream_t stream) {
  const float* x = (const float*)d_in[0];
  const float* Wq = (const float*)d_in[1];
  const float* keys = (const float*)d_in[2];
  const float* values = (const float*)d_in[3];
  const float* attn_scale = (const float*)d_in[4];
  const float* Wo = (const float*)d_in[5];
  float* out = (float*)d_out;

  char* ws = (char*)d_ws;
  unsigned short* xb = (unsigned short*)(ws);                   // 8 MB
  unsigned short* wqt = (unsigned short*)(ws + (8ull << 20));   // 2 MB
  unsigned short* wot = (unsigned short*)(ws + (10ull << 20));  // 2 MB
  unsigned short* kbf = (unsigned short*)(ws + (12ull << 20));  // 4 MB
  unsigned short* vt = (unsigned short*)(ws + (16ull << 20));   // 4 MB
  unsigned short* qbf = (unsigned short*)(ws + (20ull << 20));  // 8 MB
  unsigned short* yb = (unsigned short*)(ws + (28ull << 20));   // 8 MB

  prep_kernel<<<12288, 256, 0, stream>>>(x, Wq, Wo, keys, values, attn_scale,
                                         (unsigned*)xb, wqt, wot, (unsigned*)kbf, vt);
  gemm_nt_kernel<true><<<dim3(8, 64), 256, 0, stream>>>(xb, wqt, nullptr, qbf,
                                                        S_LEN, DM, DM);
  attn_kernel<<<dim3(8, 64), 256, 0, stream>>>(qbf, kbf, vt, attn_scale, yb);
  gemm_nt_kernel<false><<<dim3(8, 64), 256, 0, stream>>>(yb, wot, out, nullptr,
                                                         S_LEN, DM, DM);
}

// Round 6
// 181.068 us; speedup vs baseline: 1.4478x; 1.3619x over previous
//
#include <hip/hip_runtime.h>
#include <math.h>

#define S_LEN 4096
#define DM 1024
#define NHEADS 8
#define HDIM 128
#define NSLOTS 2048

typedef __attribute__((ext_vector_type(8))) short bf16x8;
typedef __attribute__((ext_vector_type(4))) float f32x4;
typedef __attribute__((ext_vector_type(16))) float f32x16;
typedef __attribute__((ext_vector_type(4))) unsigned u32x4;

static __device__ __forceinline__ unsigned short f2bf(float f) {
  union { float f; unsigned u; } v; v.f = f;
  unsigned u = v.u;
  return (unsigned short)((u + 0x7fffu + ((u >> 16) & 1u)) >> 16);
}
static __device__ __forceinline__ unsigned pack2(float a, float b) {
  return (unsigned)f2bf(a) | ((unsigned)f2bf(b) << 16);
}
static __device__ __forceinline__ f32x4 mfma16(bf16x8 a, bf16x8 b, f32x4 c) {
  return __builtin_amdgcn_mfma_f32_16x16x32_bf16(a, b, c, 0, 0, 0);
}
static __device__ __forceinline__ f32x16 mfma32(bf16x8 a, bf16x8 b, f32x16 c) {
  return __builtin_amdgcn_mfma_f32_32x32x16_bf16(a, b, c, 0, 0, 0);
}
static __device__ __forceinline__ void gll16(const void* g, void* l) {
  __builtin_amdgcn_global_load_lds(
      (__attribute__((address_space(1))) void*)(void*)(unsigned long long)(const char*)g,
      (__attribute__((address_space(3))) void*)l, 16, 0, 0);
}
static __device__ __forceinline__ float fexp2(float x) {
  float r;
  asm("v_exp_f32 %0, %1" : "=v"(r) : "v"(x));
  return r;
}

// =============================================================================
// IMAGE LAYOUTS (all offsets in shorts):
// A_img (M x K):  ((srow>>6)*(K/64) + (k>>6))*4096 + ((k>>3)&7)*512
//                 + (srow&63)*8 + (k&7)
// B_img (N x K):  ((n>>7)*(K/64) + (k>>6))*8192 + (((k>>3)&7)*2 + ((n>>6)&1))*512
//                 + (n&63)*8 + (k&7)          [Bt[n][k] = W[k][n]]
// K_img (h,slot,d): h*262144 + (slot>>6)*8192 + (((slot>>5)&1)*8 + (d>>4))*512
//                 + ((d>>3)&1)*256 + (slot&31)*8 + (d&7)
// V_img (h,slot,d): h*262144 + (slot>>6)*8192 + (((slot>>3)&7)*128 + d)*8 + (slot&7)
// Every kernel stages these with DMA reading 1 KB CONTIGUOUS per instruction.
// =============================================================================

__global__ __launch_bounds__(256) void prep_kernel(
    const float* __restrict__ x, const float* __restrict__ Wq,
    const float* __restrict__ Wo, const float* __restrict__ keys,
    const float* __restrict__ values, const float* __restrict__ scale,
    unsigned short* __restrict__ xb, unsigned short* __restrict__ wqt,
    unsigned short* __restrict__ wot, unsigned* __restrict__ kbf_w,
    unsigned short* __restrict__ vt) {
  __shared__ float tileU[64 * 129];
  int b = blockIdx.x, t = threadIdx.x;

  if (b < 1024) {  // ---- x -> A_img (xb): tile (mb, kb64), 64 rows x 64 k ----
    int mb = b >> 4, kb64 = b & 15;
#pragma unroll
    for (int p = 0; p < 4; p++) {
      int fi = t + 256 * p;  // 0..1023 float4s
      int row = fi >> 4, kq = fi & 15;
      float4 v = *(const float4*)(x + ((size_t)(mb * 64 + row) * DM + kb64 * 64 + kq * 4));
      float* d = &tileU[row * 65 + kq * 4];
      d[0] = v.x; d[1] = v.y; d[2] = v.z; d[3] = v.w;
    }
    __syncthreads();
#pragma unroll
    for (int p2 = 0; p2 < 2; p2++) {
      int g = t + 256 * p2;  // 0..511
      int kb = g >> 6, row = g & 63;
      const float* src = &tileU[row * 65 + kb * 8];
      u32x4 w;
#pragma unroll
      for (int q = 0; q < 4; q++) w[q] = pack2(src[2 * q], src[2 * q + 1]);
      *(u32x4*)(xb + ((size_t)(mb * 16 + kb64) * 8 + kb) * 512 + row * 8) = w;
    }
  } else if (b < 1280) {  // ---- Wq/Wo -> B_img: tile (nb, kb64), 64 k x 128 n ----
    int b2 = b - 1024;
    const float* W = (b2 < 128) ? Wq : Wo;
    unsigned short* WT = (b2 < 128) ? wqt : wot;
    int r = b2 & 127;
    int nb = r >> 4, kb64 = r & 15;
#pragma unroll
    for (int p = 0; p < 8; p++) {
      int fi = t + 256 * p;  // 0..2047 float4s
      int krow = fi >> 5, nq = fi & 31;
      float4 v = *(const float4*)(W + ((size_t)(kb64 * 64 + krow) * DM + nb * 128 + nq * 4));
      float* d = &tileU[krow * 129 + nq * 4];
      d[0] = v.x; d[1] = v.y; d[2] = v.z; d[3] = v.w;
    }
    __syncthreads();
#pragma unroll
    for (int p2 = 0; p2 < 4; p2++) {
      int g = t + 256 * p2;  // 0..1023
      int pp = g >> 6, r6 = g & 63;
      int kb = pp >> 1, rh = pp & 1;
      u32x4 w;
#pragma unroll
      for (int q = 0; q < 4; q++)
        w[q] = pack2(tileU[(kb * 8 + 2 * q) * 129 + rh * 64 + r6],
                     tileU[(kb * 8 + 2 * q + 1) * 129 + rh * 64 + r6]);
      *(u32x4*)(WT + ((size_t)(nb * 16 + kb64) * 16 + pp) * 512 + r6 * 8) = w;
    }
  } else if (b < 5376) {  // ---- keys -> K_img: normalize + fold scale ----
    int b3 = b - 1280;
    int w = b3 * 4 + (t >> 6);  // row 0..16383
    int lane = t & 63;
    int slot = w >> 3, h = w & 7;
    float2 v = ((const float2*)(keys + (size_t)w * HDIM))[lane];
    float ss = v.x * v.x + v.y * v.y;
#pragma unroll
    for (int m = 1; m < 64; m <<= 1) ss += __shfl_xor(ss, m);
    float sc = scale[h] * rsqrtf(ss + 1e-6f);
    // d = 2*lane
    size_t off = (size_t)h * 131072 + (slot >> 6) * 4096 +
                 (((slot >> 5) & 1) * 8 + (lane >> 3)) * 256 + ((lane >> 2) & 1) * 128 +
                 (slot & 31) * 4 + (lane & 3);
    kbf_w[off] = pack2(v.x * sc, v.y * sc);
  } else {  // ---- values -> V_img: tile (h, chunk c): 64 slots x 128 d ----
    int b4 = b - 5376;
    int h = b4 >> 5, c = b4 & 31;
#pragma unroll
    for (int p = 0; p < 8; p++) {
      int fi = t + 256 * p;  // 0..2047 float4s
      int srow = fi >> 5, dq = fi & 31;
      float4 v = *(const float4*)(values +
                                  ((size_t)((c * 64 + srow) * NHEADS + h) * HDIM + dq * 4));
      float* d = &tileU[srow * 129 + dq * 4];
      d[0] = v.x; d[1] = v.y; d[2] = v.z; d[3] = v.w;
    }
    __syncthreads();
#pragma unroll
    for (int p2 = 0; p2 < 4; p2++) {
      int g = t + 256 * p2;  // 0..1023
      int sb = g >> 7, d = g & 127;
      u32x4 w;
#pragma unroll
      for (int q = 0; q < 4; q++)
        w[q] = pack2(tileU[(sb * 8 + 2 * q) * 129 + d], tileU[(sb * 8 + 2 * q + 1) * 129 + d]);
      *(u32x4*)(vt + (size_t)h * 262144 + c * 8192 + (sb * 128 + d) * 8) = w;
    }
  }
}

// ---- GEMM: C(MxN) = A(A_img) * Bt(B_img)^T. 64x128 tile, 4 waves, BK=64, ----
// double-buffered LDS, all DMA 1KB-contiguous. Frag reads as before (verified).
template <bool FUSE_QNORM>
__global__ __launch_bounds__(256) void gemm_nt_kernel(const unsigned short* __restrict__ A,
                                                      const unsigned short* __restrict__ Bt,
                                                      float* __restrict__ Cf,
                                                      unsigned short* __restrict__ Cq,
                                                      int M, int N, int K) {
  __shared__ __align__(16) unsigned short As2[2][4096];
  __shared__ __align__(16) unsigned short Bs2[2][8192];
  __shared__ float ssq[64][2];
  int t = threadIdx.x;
  int wave = t >> 6, lane = t & 63;
  int l16 = lane & 15, quad = lane >> 4;
  int m_blk = blockIdx.y * 64, n_blk = blockIdx.x * 128;
  int wm = (wave & 1) * 32, wn = (wave >> 1) * 64;
  int nk64 = K >> 6;
  f32x4 zero = {0.f, 0.f, 0.f, 0.f};
  f32x4 acc[2][4];
#pragma unroll
  for (int i = 0; i < 2; i++)
#pragma unroll
    for (int j = 0; j < 4; j++) acc[i][j] = zero;

  auto stage = [&](int k0, int b) {
    int kb64 = k0 >> 6;
    const unsigned short* Abase = A + ((size_t)(blockIdx.y * nk64 + kb64)) * 4096;
    const unsigned short* Bbase = Bt + ((size_t)(blockIdx.x * nk64 + kb64)) * 8192;
#pragma unroll
    for (int i = 0; i < 2; i++) {
      int kb = wave * 2 + i;
      gll16(Abase + kb * 512 + lane * 8, &As2[b][kb * 512]);
    }
#pragma unroll
    for (int i = 0; i < 4; i++) {
      int j = wave * 4 + i;
      gll16(Bbase + j * 512 + lane * 8, &Bs2[b][j * 512]);
    }
  };

  stage(0, 0);
  for (int k0 = 0; k0 < K; k0 += 64) {
    int b = (k0 >> 6) & 1;
    __syncthreads();
    if (k0 + 64 < K) stage(k0 + 64, b ^ 1);
#pragma unroll
    for (int kk = 0; kk < 2; kk++) {
      bf16x8 af[2], bfr[4];
#pragma unroll
      for (int mt = 0; mt < 2; mt++)
        af[mt] = *(const bf16x8*)&As2[b][((kk * 4 + quad) * 64 + wm + mt * 16 + l16) * 8];
#pragma unroll
      for (int nt = 0; nt < 4; nt++)
        bfr[nt] = *(const bf16x8*)&Bs2[b][((kk * 4 + quad) * 128 + wn + nt * 16 + l16) * 8];
#pragma unroll
      for (int mt = 0; mt < 2; mt++)
#pragma unroll
        for (int nt = 0; nt < 4; nt++) acc[mt][nt] = mfma16(af[mt], bfr[nt], acc[mt][nt]);
    }
  }

  if (FUSE_QNORM) {
#pragma unroll
    for (int mt = 0; mt < 2; mt++)
#pragma unroll
      for (int r = 0; r < 4; r++) {
        float s = 0.f;
#pragma unroll
        for (int nt = 0; nt < 4; nt++) s += acc[mt][nt][r] * acc[mt][nt][r];
#pragma unroll
        for (int d = 1; d < 16; d <<= 1) s += __shfl_xor(s, d);
        if (l16 == 0) ssq[wm + mt * 16 + quad * 4 + r][wave >> 1] = s;
      }
    __syncthreads();
#pragma unroll
    for (int mt = 0; mt < 2; mt++)
#pragma unroll
      for (int r = 0; r < 4; r++) {
        int row = wm + mt * 16 + quad * 4 + r;
        float rs = rsqrtf(ssq[row][0] + ssq[row][1] + 1e-6f) * 1.44269504f;
#pragma unroll
        for (int nt = 0; nt < 4; nt++)
          Cq[(size_t)(m_blk + row) * N + n_blk + wn + nt * 16 + l16] =
              f2bf(acc[mt][nt][r] * rs);
      }
  } else {
#pragma unroll
    for (int mt = 0; mt < 2; mt++)
#pragma unroll
      for (int nt = 0; nt < 4; nt++)
#pragma unroll
        for (int r = 0; r < 4; r++)
          Cf[(size_t)(m_blk + wm + mt * 16 + quad * 4 + r) * N + n_blk + wn + nt * 16 +
             l16] = acc[mt][nt][r];
  }
}

// ---- flash attention vs fixed memory bank -----------------------------------
// As round 5 (2 q-groups x 2 slot-splits, 32 rows/wave, K LDS-dbuf, V VGPR-dbuf,
// static max, split-K combine) but ALL staging reads are 1KB-contiguous from
// K_img / V_img. Output written in A_img layout for gemm2.
__global__ __launch_bounds__(256, 2) void attn_kernel(const unsigned short* __restrict__ qbf,
                                                      const unsigned short* __restrict__ kbf,
                                                      const unsigned short* __restrict__ vt,
                                                      const float* __restrict__ scale,
                                                      unsigned short* __restrict__ yb) {
  __shared__ __align__(16) char smem[43008];
  unsigned short(*Ks)[8192] = (unsigned short(*)[8192])smem;
  unsigned short(*pbuf)[32][40] = (unsigned short(*)[32][40])(smem + 32768);
  int h = blockIdx.x, t = threadIdx.x;
  int wave = t >> 6, lane = t & 63;
  int l32 = lane & 31, h8 = lane >> 5;
  int g = wave >> 1, s = wave & 1;
  int q0 = blockIdx.y * 64 + g * 32;
  const unsigned short* Kh = kbf + (size_t)h * 262144;
  const unsigned short* Vh = vt + (size_t)h * 262144;
  float M2 = fabsf(scale[h]) * 1.44269504f;

  bf16x8 aq[8];
  const unsigned short* qrow = qbf + (size_t)(q0 + l32) * DM + h * HDIM + h8 * 8;
#pragma unroll
  for (int dt = 0; dt < 8; dt++) aq[dt] = *(const bf16x8*)(qrow + dt * 16);

  f32x16 zero16 = {};
  f32x16 O[4];
#pragma unroll
  for (int i = 0; i < 4; i++) O[i] = zero16;
  float lsum[16];
#pragma unroll
  for (int r = 0; r < 16; r++) lsum[r] = 0.f;

  auto stage = [&](int c, int b) {
#pragma unroll
    for (int ii = 0; ii < 4; ii++) {
      int j = wave * 4 + ii;
      gll16(Kh + (size_t)c * 8192 + j * 512 + lane * 8, &Ks[b][j * 512]);
    }
  };
  auto loadV = [&](bf16x8(&V)[8], int c) {
#pragma unroll
    for (int nt = 0; nt < 4; nt++)
#pragma unroll
      for (int ks = 0; ks < 2; ks++)
        V[nt * 2 + ks] = *(const bf16x8*)(Vh + (size_t)c * 8192 +
                                          ((s * 4 + ks * 2 + h8) * 128 + nt * 32 + l32) * 8);
  };
  auto body = [&](const unsigned short* Kbuf, bf16x8(&V)[8]) {
    f32x16 acc0 = zero16, acc1 = zero16;
#pragma unroll
    for (int dt = 0; dt < 4; dt++) {
      bf16x8 k0 = *(const bf16x8*)&Kbuf[s * 4096 + ((4 * dt + h8) * 32 + l32) * 8];
      bf16x8 k1 = *(const bf16x8*)&Kbuf[s * 4096 + ((4 * dt + 2 + h8) * 32 + l32) * 8];
      acc0 = mfma32(aq[2 * dt], k0, acc0);
      acc1 = mfma32(aq[2 * dt + 1], k1, acc1);
    }
    f32x16 acc = acc0 + acc1;
#pragma unroll
    for (int r = 0; r < 16; r++) {
      float p = fexp2(acc[r] - M2);
      lsum[r] += p;
      pbuf[wave][(r & 3) + 8 * (r >> 2) + 4 * h8][l32] = f2bf(p);
    }
    bf16x8 pa[2];
#pragma unroll
    for (int ks = 0; ks < 2; ks++)
      pa[ks] = *(const bf16x8*)&pbuf[wave][l32][ks * 16 + h8 * 8];
#pragma unroll
    for (int nt = 0; nt < 4; nt++) {
      f32x16 o = O[nt];
      o = mfma32(pa[0], V[nt * 2 + 0], o);
      o = mfma32(pa[1], V[nt * 2 + 1], o);
      O[nt] = o;
    }
  };

  bf16x8 Vreg0[8], Vreg1[8];
  constexpr int NC = NSLOTS / 64;  // 32
  stage(0, 0);
  loadV(Vreg0, 0);
  for (int cc = 0; cc < NC; cc += 2) {
    __syncthreads();
    if (cc + 1 < NC) {
      stage(cc + 1, 1);
      loadV(Vreg1, cc + 1);
    }
    body(&Ks[0][0], Vreg0);
    __syncthreads();
    if (cc + 2 < NC) {
      stage(cc + 2, 0);
      loadV(Vreg0, cc + 2);
    }
    body(&Ks[1][0], Vreg1);
  }

  // ---- split-K combine (exact: static max), output in A_img layout ----
  __syncthreads();
  float(*Oc)[32][128] = (float(*)[32][128])smem;
  float(*Lc)[32][32] = (float(*)[32][32])(smem + 32768);
  if (s == 1) {
#pragma unroll
    for (int nt = 0; nt < 4; nt++)
#pragma unroll
      for (int r = 0; r < 16; r++)
        Oc[g][(r & 3) + 8 * (r >> 2) + 4 * h8][nt * 32 + l32] = O[nt][r];
#pragma unroll
    for (int r = 0; r < 16; r++) Lc[g][(r & 3) + 8 * (r >> 2) + 4 * h8][l32] = lsum[r];
  }
  __syncthreads();
  if (s == 0) {
#pragma unroll
    for (int r = 0; r < 16; r++) {
      int row = (r & 3) + 8 * (r >> 2) + 4 * h8;
      float sum = lsum[r] + Lc[g][row][l32];
#pragma unroll
      for (int d = 1; d < 32; d <<= 1) sum += __shfl_xor(sum, d);
      float inv = 1.0f / sum;
#pragma unroll
      for (int nt = 0; nt < 4; nt++) {
        float v = O[nt][r] + Oc[g][row][nt * 32 + l32];
        size_t off = ((size_t)blockIdx.y * 16 + h * 2 + (nt >> 1)) * 4096 +
                     ((nt & 1) * 4 + (l32 >> 3)) * 512 + (g * 32 + row) * 8 + (l32 & 7);
        yb[off] = f2bf(v * inv);
      }
    }
  }
}

// ---- launcher ---------------------------------------------------------------

extern "C" void kernel_launch(void* const* d_in, const int* in_sizes, int n_in,
                              void* d_out, int out_size, void* d_ws, size_t ws_size,
                              hipStream_t stream) {
  const float* x = (const float*)d_in[0];
  const float* Wq = (const float*)d_in[1];
  const float* keys = (const float*)d_in[2];
  const float* values = (const float*)d_in[3];
  const float* attn_scale = (const float*)d_in[4];
  const float* Wo = (const float*)d_in[5];
  float* out = (float*)d_out;

  char* ws = (char*)d_ws;
  unsigned short* xb = (unsigned short*)(ws);                   // 8 MB  (A_img)
  unsigned short* wqt = (unsigned short*)(ws + (8ull << 20));   // 2 MB  (B_img)
  unsigned short* wot = (unsigned short*)(ws + (10ull << 20));  // 2 MB  (B_img)
  unsigned short* kbf = (unsigned short*)(ws + (12ull << 20));  // 4 MB  (K_img)
  unsigned short* vt = (unsigned short*)(ws + (16ull << 20));   // 4 MB  (V_img)
  unsigned short* qbf = (unsigned short*)(ws + (20ull << 20));  // 8 MB  (linear)
  unsigned short* yb = (unsigned short*)(ws + (28ull << 20));   // 8 MB  (A_img)

  prep_kernel<<<5632, 256, 0, stream>>>(x, Wq, Wo, keys, values, attn_scale, xb, wqt, wot,
                                        (unsigned*)kbf, vt);
  gemm_nt_kernel<true><<<dim3(8, 64), 256, 0, stream>>>(xb, wqt, nullptr, qbf,
                                                        S_LEN, DM, DM);
  attn_kernel<<<dim3(8, 64), 256, 0, stream>>>(qbf, kbf, vt, attn_scale, yb);
  gemm_nt_kernel<false><<<dim3(8, 64), 256, 0, stream>>>(yb, wot, out, nullptr,
                                                         S_LEN, DM, DM);
}